// Round 1
// baseline (315.528 us; speedup 1.0000x reference)
//
#include <hip/hip_runtime.h>
#include <math.h>

#define KK 200
#define MM 256
#define NEPTS 200
#define NI 199   // NE-1 increments
#define HH 16

__device__ __forceinline__ float fast_tanh(float x) {
  // tanh(x) = 1 - 2/(exp(2x)+1); saturates correctly for |x| large
  float e = __expf(2.0f * x);
  return 1.0f - 2.0f * __builtin_amdgcn_rcpf(e + 1.0f);
}

__global__ __launch_bounds__(256) void lt_kernel1(
    const float* __restrict__ t0,
    const float* __restrict__ noise,
    const float* __restrict__ gW1,
    const float* __restrict__ gb1,
    const float* __restrict__ gW2,
    const float* __restrict__ gb2,
    const float* __restrict__ gW3,
    const float* __restrict__ gb3,
    float* __restrict__ s_out) {
  __shared__ float sW1[HH], sB1[HH], sW2T[HH * HH], sB2[HH], sW3[HH];
  __shared__ float sB3;
  const int tid = threadIdx.x;
  if (tid < HH) {
    sW1[tid] = gW1[tid];
    sB1[tid] = gb1[tid];
    sB2[tid] = gb2[tid];
    sW3[tid] = gW3[tid];
  }
  if (tid == 0) sB3 = gb3[0];
  {
    int j = tid >> 4, i = tid & 15;
    sW2T[i * HH + j] = gW2[j * HH + i];   // transpose so inner loop is contiguous
  }
  __syncthreads();

  const int wave = tid >> 6, lane = tid & 63;
  const int pair = blockIdx.x * 4 + wave;          // pair = k*MM + m
  const int k = pair / MM;
  const int m = pair - k * MM;

  const float t0m = t0[m];
  const float dt0 = t0[m + 1] - t0m;
  const float inv199 = 1.0f / (float)NI;

  const float* nrow = noise + ((size_t)k * MM + m) * NI;

  // ---- pass 1: increments + wave-level inclusive scan over the 199 steps ----
  float incr[4], dte[4], IS[4];
  float carry = 0.0f;
#pragma unroll
  for (int c = 0; c < 4; ++c) {
    int jd = c * 64 + lane;
    float fj  = (float)jd * inv199;
    float fj1 = (float)(jd + 1) * inv199;
    float e0 = t0m + fj * dt0;     // mimic reference f32 e_time construction
    float e1 = t0m + fj1 * dt0;
    float d = e1 - e0;
    dte[c] = d;
    float v = 0.0f;
    if (jd < NI) v = nrow[jd] * sqrtf(d);
    incr[c] = v;
    float x = v;
#pragma unroll
    for (int off = 1; off < 64; off <<= 1) {
      float y = __shfl_up(x, off, 64);
      if (lane >= off) x += y;
    }
    IS[c] = carry + x;                       // = W[jd+1]
    carry += __shfl(x, 63, 64);              // chunk total
  }
  const float Wfin = carry;                  // = W[199] (invalid lanes added 0)

  // ---- bridge endpoints for each owned point ----
  float xj[4], dxv[4];
#pragma unroll
  for (int c = 0; c < 4; ++c) {
    int jd = c * 64 + lane;
    float fj  = (float)jd * inv199;
    float fj1 = (float)(jd + 1) * inv199;
    float Wj1 = IS[c];
    float Wj  = Wj1 - incr[c];
    float a0 = fabsf(Wj  - fj  * Wfin);
    float a1 = fabsf(Wj1 - fj1 * Wfin);
    xj[c]  = a0;
    dxv[c] = a1 - a0;
  }

  // ---- MLP layer 1 (4 points register-blocked) ----
  float h1[4][HH];
#pragma unroll
  for (int i = 0; i < HH; ++i) {
    float w = sW1[i], bb = sB1[i];
#pragma unroll
    for (int c = 0; c < 4; ++c) h1[c][i] = fast_tanh(fmaf(xj[c], w, bb));
  }

  // ---- layers 2 + 3 ----
  float mu0 = sB3, mu1 = sB3, mu2 = sB3, mu3 = sB3;
#pragma unroll
  for (int i2 = 0; i2 < HH; ++i2) {
    float bb = sB2[i2];
    float a0 = bb, a1 = bb, a2 = bb, a3 = bb;
#pragma unroll
    for (int i1 = 0; i1 < HH; ++i1) {
      float w = sW2T[i2 * HH + i1];
      a0 = fmaf(h1[0][i1], w, a0);
      a1 = fmaf(h1[1][i1], w, a1);
      a2 = fmaf(h1[2][i1], w, a2);
      a3 = fmaf(h1[3][i1], w, a3);
    }
    float w3 = sW3[i2];
    mu0 = fmaf(fast_tanh(a0), w3, mu0);
    mu1 = fmaf(fast_tanh(a1), w3, mu1);
    mu2 = fmaf(fast_tanh(a2), w3, mu2);
    mu3 = fmaf(fast_tanh(a3), w3, mu3);
  }

  float muv[4] = {mu0, mu1, mu2, mu3};
  float accA = 0.0f, accB = 0.0f;
#pragma unroll
  for (int c = 0; c < 4; ++c) {
    int jd = c * 64 + lane;
    if (jd < NI) {
      accA = fmaf(muv[c], dxv[c], accA);
      accB = fmaf(muv[c] * muv[c], dte[c], accB);
    }
  }
#pragma unroll
  for (int off = 32; off > 0; off >>= 1) {
    accA += __shfl_xor(accA, off, 64);
    accB += __shfl_xor(accB, off, 64);
  }
  if (lane == 0) s_out[pair] = accA - 0.5f * accB;
}

__global__ __launch_bounds__(256) void lt_kernel2(
    const float* __restrict__ t0, const float* __restrict__ s_in,
    float* __restrict__ out) {
  const int m = threadIdx.x;
  // online stable logsumexp over k
  float mx = -INFINITY, sum = 0.0f;
  for (int k = 0; k < KK; ++k) {
    float s = s_in[k * MM + m];
    if (s > mx) {
      sum = sum * __expf(mx - s) + 1.0f;
      mx = s;
    } else {
      sum += __expf(s - mx);
    }
  }
  float expect = logf(sum) + mx - logf((float)KK);
  float t0m = t0[m], dt0 = t0[m + 1] - t0m;
  const float eps = 0.01f;
  float p = logf(eps + 1e-7f) + 0.5f * logf(0.6366197723675814f)
          - 2.0f * eps * eps / dt0 - logf(dt0 * sqrtf(dt0) + 1e-7f);
  float val = p + expect;

  __shared__ float red[4];
#pragma unroll
  for (int off = 32; off > 0; off >>= 1) val += __shfl_xor(val, off, 64);
  int lane = m & 63, w = m >> 6;
  if (lane == 0) red[w] = val;
  __syncthreads();
  if (m == 0) out[0] = (red[0] + red[1] + red[2] + red[3]) / (float)MM;
}

extern "C" void kernel_launch(void* const* d_in, const int* in_sizes, int n_in,
                              void* d_out, int out_size, void* d_ws, size_t ws_size,
                              hipStream_t stream) {
  const float* t0    = (const float*)d_in[0];
  const float* noise = (const float*)d_in[1];
  const float* W1    = (const float*)d_in[2];
  const float* b1    = (const float*)d_in[3];
  const float* W2    = (const float*)d_in[4];
  const float* b2    = (const float*)d_in[5];
  const float* W3    = (const float*)d_in[6];
  const float* b3    = (const float*)d_in[7];
  float* s_ws = (float*)d_ws;                     // K*M floats = 204800 B
  float* out  = (float*)d_out;

  lt_kernel1<<<(KK * MM) / 4, 256, 0, stream>>>(t0, noise, W1, b1, W2, b2, W3, b3, s_ws);
  lt_kernel2<<<1, 256, 0, stream>>>(t0, s_ws, out);
}

// Round 3
// 128.074 us; speedup vs baseline: 2.4636x; 2.4636x over previous
//
#include <hip/hip_runtime.h>
#include <math.h>

#define KK 200
#define MM 256
#define NI 199      // NE-1 increments
#define HH 16
#define TBLN 4096
#define XMAX 16.0f
#define INVH 256.0f // TBLN / XMAX

// ---------------- kernel 0: build mu(x) lookup table ----------------
__global__ __launch_bounds__(256) void lt_table(
    const float* __restrict__ W1, const float* __restrict__ b1,
    const float* __restrict__ W2, const float* __restrict__ b2,
    const float* __restrict__ W3, const float* __restrict__ b3,
    float* __restrict__ tbl) {
  int i = blockIdx.x * 256 + threadIdx.x;
  if (i >= TBLN) return;
  float x = (float)i * (XMAX / (float)TBLN);
  float h1[HH];
#pragma unroll
  for (int j = 0; j < HH; ++j) h1[j] = tanhf(fmaf(x, W1[j], b1[j]));
  float mu = b3[0];
#pragma unroll
  for (int i2 = 0; i2 < HH; ++i2) {
    float z = b2[i2];
#pragma unroll
    for (int j = 0; j < HH; ++j) z = fmaf(h1[j], W2[j * HH + i2], z);
    mu = fmaf(tanhf(z), W3[i2], mu);
  }
  tbl[i] = mu;
}

// ---------------- kernel 1: scan + bridge + table-mu + per-(k,m) sum ----------------
__global__ __launch_bounds__(1024) void lt_main(
    const float* __restrict__ t0,
    const float* __restrict__ noise,
    const float* __restrict__ tbl,
    float* __restrict__ s_out) {
  __shared__ float sT[TBLN];
  const int tid = threadIdx.x;
#pragma unroll
  for (int i = 0; i < TBLN / 1024; ++i) sT[tid + i * 1024] = tbl[tid + i * 1024];
  __syncthreads();

  const int wave = tid >> 6, lane = tid & 63;
  const int pair = blockIdx.x * 16 + wave;     // pair = k*256 + m
  const int m = pair & 255;

  const float t0m = t0[m];
  const float dt0 = t0[m + 1] - t0m;
  const float inv199 = 1.0f / 199.0f;

  const float* nrow = noise + (size_t)pair * NI;
  const int p0 = lane * 4;

  // load 4 consecutive noise increments (masked tail)
  float nv[4];
  if (p0 + 3 < NI) {
    nv[0] = nrow[p0]; nv[1] = nrow[p0 + 1]; nv[2] = nrow[p0 + 2]; nv[3] = nrow[p0 + 3];
  } else {
#pragma unroll
    for (int c = 0; c < 4; ++c) nv[c] = (p0 + c < NI) ? nrow[p0 + c] : 0.0f;
  }

  // e_time fractions (mimic reference f32 arithmetic)
  float f[5], e[5];
#pragma unroll
  for (int c = 0; c < 5; ++c) {
    f[c] = (float)(p0 + c) * inv199;
    e[c] = t0m + f[c] * dt0;
  }

  float dte[4], cum[5];
  cum[0] = 0.0f;
#pragma unroll
  for (int c = 0; c < 4; ++c) {
    dte[c] = e[c + 1] - e[c];
    float v = (p0 + c < NI) ? nv[c] * sqrtf(dte[c]) : 0.0f;
    cum[c + 1] = cum[c] + v;
  }
  const float tot = cum[4];

  // wave-level inclusive scan of per-lane totals
  float x = tot;
#pragma unroll
  for (int off = 1; off < 64; off <<= 1) {
    float y = __shfl_up(x, off, 64);
    if (lane >= off) x += y;
  }
  const float prefix = x - tot;          // exclusive prefix = W[4*lane]
  const float Wfin = __shfl(x, 63, 64);  // W[199]

  // bridge |W - frac*Wfin| at the 5 owned points
  float xb[5];
#pragma unroll
  for (int c = 0; c < 5; ++c) xb[c] = fabsf((prefix + cum[c]) - f[c] * Wfin);

  // mu via LDS lerp table; accumulate s = sum(mu*dx - 0.5*mu^2*dt)
  float sp = 0.0f;
#pragma unroll
  for (int c = 0; c < 4; ++c) {
    if (p0 + c < NI) {
      float xc = fminf(xb[c], XMAX - 2.0f / INVH);
      float tt = xc * INVH;
      int ix = (int)tt;
      float fr = tt - (float)ix;
      float T0 = sT[ix], T1 = sT[ix + 1];
      float mu = fmaf(fr, T1 - T0, T0);
      float dx = xb[c + 1] - xb[c];
      sp += mu * dx - 0.5f * mu * mu * dte[c];
    }
  }
#pragma unroll
  for (int off = 32; off > 0; off >>= 1) sp += __shfl_xor(sp, off, 64);
  if (lane == 0) {
    int k = pair >> 8;
    s_out[m * KK + k] = sp;              // transposed [M][K] for kernel2 locality
  }
}

// ---------------- kernel 2: per-m logsumexp over K + p-term + mean ----------------
__global__ __launch_bounds__(1024) void lt_finish(
    const float* __restrict__ t0, const float* __restrict__ s_in,
    float* __restrict__ out) {
  const int t = threadIdx.x;
  const int m = t >> 2, q = t & 3;
  const float* row = s_in + m * KK + q * 50;

  float mx = -INFINITY, sum = 0.0f;
#pragma unroll 5
  for (int i = 0; i < 50; ++i) {
    float s = row[i];
    float nm = fmaxf(mx, s);
    sum = sum * __expf(mx - nm) + __expf(s - nm);
    mx = nm;
  }
  // merge the 4 partials per m (lanes differ only in bits 0..1)
#pragma unroll
  for (int off = 1; off < 4; off <<= 1) {
    float omx = __shfl_xor(mx, off, 64);
    float osum = __shfl_xor(sum, off, 64);
    float nm = fmaxf(mx, omx);
    sum = sum * __expf(mx - nm) + osum * __expf(omx - nm);
    mx = nm;
  }

  float val = 0.0f;
  if (q == 0) {
    float expect = logf(sum) + mx - logf(200.0f);
    float t0m = t0[m], d = t0[m + 1] - t0m;
    const float eps = 0.01f;
    float p = logf(eps + 1e-7f) + 0.5f * logf(0.6366197723675814f)
            - 2.0f * eps * eps / d - logf(d * sqrtf(d) + 1e-7f);
    val = p + expect;
  }
#pragma unroll
  for (int off = 32; off > 0; off >>= 1) val += __shfl_xor(val, off, 64);

  __shared__ float red[16];
  const int lane = t & 63, w = t >> 6;
  if (lane == 0) red[w] = val;
  __syncthreads();
  if (t == 0) {
    float s2 = 0.0f;
#pragma unroll
    for (int i = 0; i < 16; ++i) s2 += red[i];
    out[0] = s2 * (1.0f / 256.0f);
  }
}

extern "C" void kernel_launch(void* const* d_in, const int* in_sizes, int n_in,
                              void* d_out, int out_size, void* d_ws, size_t ws_size,
                              hipStream_t stream) {
  const float* t0    = (const float*)d_in[0];
  const float* noise = (const float*)d_in[1];
  const float* W1    = (const float*)d_in[2];
  const float* b1    = (const float*)d_in[3];
  const float* W2    = (const float*)d_in[4];
  const float* b2    = (const float*)d_in[5];
  const float* W3    = (const float*)d_in[6];
  const float* b3    = (const float*)d_in[7];

  float* s_ws = (float*)d_ws;            // [M][K] = 51200 floats (204800 B)
  float* tbl  = s_ws + KK * MM;          // 4096 floats (16384 B), total 221184 B
  float* out  = (float*)d_out;

  lt_table<<<TBLN / 256, 256, 0, stream>>>(W1, b1, W2, b2, W3, b3, tbl);
  lt_main<<<(KK * MM) / 16, 1024, 0, stream>>>(t0, noise, tbl, s_ws);
  lt_finish<<<1, 1024, 0, stream>>>(t0, s_ws, out);
}